// Round 4
// baseline (753.522 us; speedup 1.0000x reference)
//
#include <hip/hip_runtime.h>
#include <math.h>

// QuaternionAttention B=4, L=S=2048, H=8, E=64, M=4 (fp32 in/out).
// MFMA flash attention, ABCD trig decomposition:
//   raw(l,s) = A*CC + B*CS + C*SC + D*SS,  logits = raw/32
// Round 4 (= round 3 + compile fix): the 4 ABCD variants are Q-SIDE chunk
// permutations (register-built once per block via ks-swap + shfl_xor(32) +
// sign masks), so K is staged PLAIN once per tile and score B-frags are
// shared across all 4 MFMAs. V transposed via 4x4 register blocks.
// cvt_pkrtz packed fp32->fp16 staging.

#define B_ 4
#define L_ 2048
#define S_ 2048
#define H_ 8
#define E_ 64
#define M_ 4
#define NTH 256

typedef _Float16 f16x2 __attribute__((ext_vector_type(2)));
typedef _Float16 f16x4 __attribute__((ext_vector_type(4)));
typedef _Float16 f16x8 __attribute__((ext_vector_type(8)));
typedef __fp16 fp16x2 __attribute__((ext_vector_type(2)));   // cvt_pkrtz return type
typedef float f32x4 __attribute__((ext_vector_type(4)));

union H4U { f16x4 h; fp16x2 p[2]; unsigned int u[2]; };
union H8U { f16x8 h; unsigned int u[4]; };

__device__ __forceinline__ f16x4 cvt4(float x, float y, float z, float w) {
    H4U r;
    r.p[0] = __builtin_amdgcn_cvt_pkrtz(x, y);
    r.p[1] = __builtin_amdgcn_cvt_pkrtz(z, w);
    return r.h;
}
__device__ __forceinline__ f16x8 shfl32(f16x8 x) {
    H8U a, r; a.h = x;
    #pragma unroll
    for (int i = 0; i < 4; ++i) r.u[i] = (unsigned)__shfl_xor((int)a.u[i], 32, 64);
    return r.h;
}
__device__ __forceinline__ f16x8 xorm(f16x8 x, unsigned m) {
    H8U a; a.h = x;
    #pragma unroll
    for (int i = 0; i < 4; ++i) a.u[i] ^= m;
    return a.h;
}

__global__ __launch_bounds__(NTH, 3)
void qattn_mfma2(const float* __restrict__ qp, const float* __restrict__ kp,
                 const float* __restrict__ vp,
                 const float* __restrict__ qo, const float* __restrict__ qt,
                 const float* __restrict__ ko, const float* __restrict__ ktt,
                 float* __restrict__ out)
{
    const int l0 = blockIdx.x * 64;
    const int h  = blockIdx.y;
    const int b  = blockIdx.z;
    const int t  = threadIdx.x;
    const int wv   = t >> 6;
    const int lane = t & 63;
    const int quad = lane >> 4;
    const int nn   = lane & 15;
    const int qh   = quad >> 1;   // quad-half = chunk bit inside an A-frag ks

    __shared__ _Float16 ks_[64][64];   // plain K tile [key][e], XOR-chunk swizzled
    __shared__ _Float16 vts[64][64];   // V^T [e][key]
    __shared__ _Float16 pss[64][64];   // Q staging, then P [row][key]
    __shared__ float ktrc[64][4], ktrs[64][4];
    __shared__ float qtrc[64][4], qtrs[64][4];

    // ---- stage Q (fp16, swizzled) + query trig ----
    {
        const float* qb = qp + ((size_t)((b * L_ + l0) * H_ + h)) * E_;
        #pragma unroll
        for (int i = 0; i < 4; ++i) {
            int idx = t + NTH * i;
            int row = idx >> 4, c16 = idx & 15;
            float4 v = *(const float4*)(qb + (size_t)row * (H_ * E_) + c16 * 4);
            int k = c16 * 4;
            int ch = ((k >> 3) ^ (row & 7));
            *(f16x4*)&pss[row][ch * 8 + (k & 7)] = cvt4(v.x, v.y, v.z, v.w);
        }
        int row = t >> 2, m = t & 3;
        size_t off = (size_t)((b * L_ + l0 + row) * H_ + h) * M_ + m;
        float ang = qo[off] * ((float)(l0 + row) * (1.0f / L_)) + qt[off];
        qtrc[row][m] = __cosf(ang);
        qtrs[row][m] = __sinf(ang);
    }
    __syncthreads();

    // ---- build the 4 Q-variant A-frag sets (once per block) ----
    // Q_A = (q0,q1,q2,q3)   Q_B = (q2,q3,-q0,-q1)
    // Q_C = (-q1,q0,q3,-q2) Q_D = (q3,-q2,q1,-q0)
    // frag chunk d = 2*ks + qh; variant frag = sign(d) * plain frag of chunk d^dx.
    // dx: B=2 (ks swap), C=1 (qh swap -> shfl 32), D=3 (both).
    f16x8 qv[4][2];
    {
        int arow = wv * 16 + nn;
        f16x8 q0, q1;
        {
            int ch0 = ((quad + 0) ^ (arow & 7));
            int ch1 = ((quad + 4) ^ (arow & 7));
            q0 = *(f16x8*)&pss[arow][ch0 * 8];
            q1 = *(f16x8*)&pss[arow][ch1 * 8];
        }
        const unsigned NEG = 0x80008000u;
        unsigned mD  = qh ? NEG : 0u;        // D: neg iff qh==1
        unsigned mC0 = qh ? 0u : NEG;        // C ks=0: neg iff qh==0
        unsigned mC1 = qh ? NEG : 0u;        // C ks=1: neg iff qh==1
        f16x8 s0 = shfl32(q0), s1 = shfl32(q1);
        qv[0][0] = q0;             qv[0][1] = q1;
        qv[1][0] = q1;             qv[1][1] = xorm(q0, NEG);
        qv[2][0] = xorm(s0, mC0);  qv[2][1] = xorm(s1, mC1);
        qv[3][0] = xorm(s1, mD);   qv[3][1] = xorm(s0, mD);
    }
    float4 qcv[4], qsv[4];
    #pragma unroll
    for (int r = 0; r < 4; ++r) {
        int row = wv * 16 + quad * 4 + r;
        qcv[r] = *(float4*)&qtrc[row][0];
        qsv[r] = *(float4*)&qtrs[row][0];
    }
    __syncthreads();   // pss now free for P

    f32x4 Oacc[4] = {{0,0,0,0},{0,0,0,0},{0,0,0,0},{0,0,0,0}};
    float mrow[4] = {-1e30f,-1e30f,-1e30f,-1e30f};
    float lrow[4] = {0.f,0.f,0.f,0.f};

    const float* kb0 = kp  + ((size_t)((b * S_) * H_ + h)) * E_;
    const float* vb0 = vp  + ((size_t)((b * S_) * H_ + h)) * E_;
    const float* kob = ko  + ((size_t)((b * S_) * H_ + h)) * M_;
    const float* ktb = ktt + ((size_t)((b * S_) * H_ + h)) * M_;

    const int kg = t >> 4;   // V-transpose: key group (4 keys)
    const int eg = t & 15;   //              e group (4 e's)

    for (int s0 = 0; s0 < S_; s0 += 64) {
        // ---- stage plain K (fp16, swizzled) ----
        #pragma unroll
        for (int i = 0; i < 4; ++i) {
            int idx = t + NTH * i;
            int key = idx >> 4, c16 = idx & 15;
            float4 kv = *(const float4*)(kb0 + (size_t)(s0 + key) * (H_ * E_) + c16 * 4);
            int k = c16 * 4;
            int ch = ((k >> 3) ^ (key & 7));
            *(f16x4*)&ks_[key][ch * 8 + (k & 7)] = cvt4(kv.x, kv.y, kv.z, kv.w);
        }
        // ---- stage V^T via 4x4 register-block transpose ----
        {
            float4 vr[4];
            #pragma unroll
            for (int j = 0; j < 4; ++j)
                vr[j] = *(const float4*)(vb0 + (size_t)(s0 + kg * 4 + j) * (H_ * E_) + eg * 4);
            #pragma unroll
            for (int e = 0; e < 4; ++e) {
                int row = eg * 4 + e;
                const float* f0 = (const float*)&vr[0];
                const float* f1 = (const float*)&vr[1];
                const float* f2 = (const float*)&vr[2];
                const float* f3 = (const float*)&vr[3];
                int ch = ((kg >> 1) ^ (row & 7));
                *(f16x4*)&vts[row][ch * 8 + (kg & 1) * 4] = cvt4(f0[e], f1[e], f2[e], f3[e]);
            }
        }
        // ---- key trig ----
        {
            int key = t >> 2, m = t & 3;
            size_t off = (size_t)(s0 + key) * (H_ * M_) + m;
            float ang = kob[off] * ((float)(s0 + key) * (1.0f / S_)) + ktb[off];
            ktrc[key][m] = __cosf(ang);
            ktrs[key][m] = __sinf(ang);
        }
        __syncthreads();

        // ---- scores: 16 rows x 64 keys, one plain K frag drives 4 variant MFMAs ----
        float sc[4][4];
        #pragma unroll
        for (int kt2 = 0; kt2 < 4; ++kt2) {
            int keyb = kt2 * 16 + nn;
            f32x4 acc[4] = {{0,0,0,0},{0,0,0,0},{0,0,0,0},{0,0,0,0}};
            #pragma unroll
            for (int ks = 0; ks < 2; ++ks) {
                int ch = ((quad + 4 * ks) ^ (nn & 7)) * 8;
                f16x8 bK = *(f16x8*)&ks_[keyb][ch];
                #pragma unroll
                for (int v = 0; v < 4; ++v)
                    acc[v] = __builtin_amdgcn_mfma_f32_16x16x32_f16(qv[v][ks], bK, acc[v], 0, 0, 0);
            }
            float4 kcv = *(float4*)&ktrc[keyb][0];
            float4 ksv = *(float4*)&ktrs[keyb][0];
            #pragma unroll
            for (int r = 0; r < 4; ++r) {
                float CC = qcv[r].x*kcv.x + qcv[r].y*kcv.y + qcv[r].z*kcv.z + qcv[r].w*kcv.w;
                float CS = qcv[r].x*ksv.x + qcv[r].y*ksv.y + qcv[r].z*ksv.z + qcv[r].w*ksv.w;
                float SC = qsv[r].x*kcv.x + qsv[r].y*kcv.y + qsv[r].z*kcv.z + qsv[r].w*kcv.w;
                float SS = qsv[r].x*ksv.x + qsv[r].y*ksv.y + qsv[r].z*ksv.z + qsv[r].w*ksv.w;
                sc[kt2][r] = (acc[0][r]*CC + acc[1][r]*CS + acc[2][r]*SC + acc[3][r]*SS) * (1.0f/32.0f);
            }
        }

        // ---- online softmax, write P (fp16, swizzled) ----
        #pragma unroll
        for (int r = 0; r < 4; ++r) {
            float tm = fmaxf(fmaxf(sc[0][r], sc[1][r]), fmaxf(sc[2][r], sc[3][r]));
            tm = fmaxf(tm, __shfl_xor(tm, 1));
            tm = fmaxf(tm, __shfl_xor(tm, 2));
            tm = fmaxf(tm, __shfl_xor(tm, 4));
            tm = fmaxf(tm, __shfl_xor(tm, 8));
            float mnew  = fmaxf(mrow[r], tm);
            float alpha = __expf(mrow[r] - mnew);
            int row = wv * 16 + quad * 4 + r;
            float psum = 0.f;
            #pragma unroll
            for (int kt2 = 0; kt2 < 4; ++kt2) {
                float p = __expf(sc[kt2][r] - mnew);
                psum += p;
                int key = kt2 * 16 + nn;
                int ch = ((key >> 3) ^ (row & 7));
                pss[row][ch * 8 + (key & 7)] = (_Float16)p;
            }
            psum += __shfl_xor(psum, 1);
            psum += __shfl_xor(psum, 2);
            psum += __shfl_xor(psum, 4);
            psum += __shfl_xor(psum, 8);
            lrow[r] = lrow[r] * alpha + psum;
            mrow[r] = mnew;
            Oacc[0][r] *= alpha; Oacc[1][r] *= alpha;
            Oacc[2][r] *= alpha; Oacc[3][r] *= alpha;
        }

        // ---- PV (wave-local P round-trip, no barrier needed) ----
        {
            int prow = wv * 16 + nn;
            #pragma unroll
            for (int ks = 0; ks < 2; ++ks) {
                int chp = ((quad + 4 * ks) ^ (prow & 7)) * 8;
                f16x8 pf = *(f16x8*)&pss[prow][chp];
                #pragma unroll
                for (int et = 0; et < 4; ++et) {
                    int e = et * 16 + nn;
                    int chv = ((quad + 4 * ks) ^ (e & 7)) * 8;
                    f16x8 vf = *(f16x8*)&vts[e][chv];
                    Oacc[et] = __builtin_amdgcn_mfma_f32_16x16x32_f16(pf, vf, Oacc[et], 0, 0, 0);
                }
            }
        }
        __syncthreads();   // protect ks_/vts/trig before next staging
    }

    // ---- epilogue ----
    float* ob = out + ((size_t)((b * L_ + l0) * H_ + h)) * E_;
    #pragma unroll
    for (int r = 0; r < 4; ++r) {
        float inv = 1.0f / lrow[r];
        int row = wv * 16 + quad * 4 + r;
        #pragma unroll
        for (int et = 0; et < 4; ++et) {
            ob[(size_t)row * (H_ * E_) + et * 16 + nn] = Oacc[et][r] * inv;
        }
    }
}

extern "C" void kernel_launch(void* const* d_in, const int* in_sizes, int n_in,
                              void* d_out, int out_size, void* d_ws, size_t ws_size,
                              hipStream_t stream) {
    const float* qp = (const float*)d_in[0];
    const float* kp = (const float*)d_in[1];
    const float* vp = (const float*)d_in[2];
    const float* qo = (const float*)d_in[3];
    const float* qt = (const float*)d_in[4];
    const float* ko = (const float*)d_in[5];
    const float* kt = (const float*)d_in[6];
    float* out = (float*)d_out;

    dim3 grid(L_ / 64, H_, B_);
    qattn_mfma2<<<grid, dim3(NTH), 0, stream>>>(qp, kp, vp, qo, qt, ko, kt, out);
}

// Round 8
// 420.445 us; speedup vs baseline: 1.7922x; 1.7922x over previous
//
#include <hip/hip_runtime.h>
#include <math.h>

// QuaternionAttention B=4, L=S=2048, H=8, E=64, M=4 (fp32 in/out).
// MFMA flash attention, ABCD trig decomposition:
//   raw(l,s) = A*CC + B*CS + C*SC + D*SS,  logits = raw/32
// Round 8 = fourth submission of the round-5 kernel (rounds 5-7 all died
// with broker "MI355X container failed twice" infra errors; no kernel
// signal). Delta vs round 4 (last successful run, 753 us WITH spills):
// removed the __launch_bounds__(,3) min-wave clamp that forced 84 VGPRs
// and scratch-spilled (WRITE_SIZE 16->300 MB, FETCH 148->850 MB).
// Structure: Q-side ABCD variant A-frags (built once/block via ks-swap +
// shfl_xor(32) + sign masks), plain-K LDS staging, 4x4 register-block V
// transpose, cvt_pkrtz packed fp32->fp16, XOR-chunk LDS swizzle.

#define B_ 4
#define L_ 2048
#define S_ 2048
#define H_ 8
#define E_ 64
#define M_ 4
#define NTH 256

typedef _Float16 f16x2 __attribute__((ext_vector_type(2)));
typedef _Float16 f16x4 __attribute__((ext_vector_type(4)));
typedef _Float16 f16x8 __attribute__((ext_vector_type(8)));
typedef __fp16 fp16x2 __attribute__((ext_vector_type(2)));   // cvt_pkrtz return type
typedef float f32x4 __attribute__((ext_vector_type(4)));

union H4U { f16x4 h; fp16x2 p[2]; unsigned int u[2]; };
union H8U { f16x8 h; unsigned int u[4]; };

__device__ __forceinline__ f16x4 cvt4(float x, float y, float z, float w) {
    H4U r;
    r.p[0] = __builtin_amdgcn_cvt_pkrtz(x, y);
    r.p[1] = __builtin_amdgcn_cvt_pkrtz(z, w);
    return r.h;
}
__device__ __forceinline__ f16x8 shfl32(f16x8 x) {
    H8U a, r; a.h = x;
    #pragma unroll
    for (int i = 0; i < 4; ++i) r.u[i] = (unsigned)__shfl_xor((int)a.u[i], 32, 64);
    return r.h;
}
__device__ __forceinline__ f16x8 xorm(f16x8 x, unsigned m) {
    H8U a; a.h = x;
    #pragma unroll
    for (int i = 0; i < 4; ++i) a.u[i] ^= m;
    return a.h;
}

__global__ __launch_bounds__(NTH)
void qattn_mfma2(const float* __restrict__ qp, const float* __restrict__ kp,
                 const float* __restrict__ vp,
                 const float* __restrict__ qo, const float* __restrict__ qt,
                 const float* __restrict__ ko, const float* __restrict__ ktt,
                 float* __restrict__ out)
{
    const int l0 = blockIdx.x * 64;
    const int h  = blockIdx.y;
    const int b  = blockIdx.z;
    const int t  = threadIdx.x;
    const int wv   = t >> 6;
    const int lane = t & 63;
    const int quad = lane >> 4;
    const int nn   = lane & 15;
    const int qh   = quad >> 1;   // quad-half = chunk bit inside an A-frag ks

    __shared__ _Float16 ks_[64][64];   // plain K tile [key][e], XOR-chunk swizzled
    __shared__ _Float16 vts[64][64];   // V^T [e][key]
    __shared__ _Float16 pss[64][64];   // Q staging, then P [row][key]
    __shared__ float ktrc[64][4], ktrs[64][4];
    __shared__ float qtrc[64][4], qtrs[64][4];

    // ---- stage Q (fp16, swizzled) + query trig ----
    {
        const float* qb = qp + ((size_t)((b * L_ + l0) * H_ + h)) * E_;
        #pragma unroll
        for (int i = 0; i < 4; ++i) {
            int idx = t + NTH * i;
            int row = idx >> 4, c16 = idx & 15;
            float4 v = *(const float4*)(qb + (size_t)row * (H_ * E_) + c16 * 4);
            int k = c16 * 4;
            int ch = ((k >> 3) ^ (row & 7));
            *(f16x4*)&pss[row][ch * 8 + (k & 7)] = cvt4(v.x, v.y, v.z, v.w);
        }
        int row = t >> 2, m = t & 3;
        size_t off = (size_t)((b * L_ + l0 + row) * H_ + h) * M_ + m;
        float ang = qo[off] * ((float)(l0 + row) * (1.0f / L_)) + qt[off];
        qtrc[row][m] = __cosf(ang);
        qtrs[row][m] = __sinf(ang);
    }
    __syncthreads();

    // ---- build the 4 Q-variant A-frag sets (once per block) ----
    // Q_A = (q0,q1,q2,q3)   Q_B = (q2,q3,-q0,-q1)
    // Q_C = (-q1,q0,q3,-q2) Q_D = (q3,-q2,q1,-q0)
    // frag chunk d = 2*ks + qh; variant frag = sign(d) * plain frag of chunk d^dx.
    // dx: B=2 (ks swap), C=1 (qh swap -> shfl 32), D=3 (both).
    f16x8 qv[4][2];
    {
        int arow = wv * 16 + nn;
        f16x8 q0, q1;
        {
            int ch0 = ((quad + 0) ^ (arow & 7));
            int ch1 = ((quad + 4) ^ (arow & 7));
            q0 = *(f16x8*)&pss[arow][ch0 * 8];
            q1 = *(f16x8*)&pss[arow][ch1 * 8];
        }
        const unsigned NEG = 0x80008000u;
        unsigned mD  = qh ? NEG : 0u;        // D: neg iff qh==1
        unsigned mC0 = qh ? 0u : NEG;        // C ks=0: neg iff qh==0
        unsigned mC1 = qh ? NEG : 0u;        // C ks=1: neg iff qh==1
        f16x8 s0 = shfl32(q0), s1 = shfl32(q1);
        qv[0][0] = q0;             qv[0][1] = q1;
        qv[1][0] = q1;             qv[1][1] = xorm(q0, NEG);
        qv[2][0] = xorm(s0, mC0);  qv[2][1] = xorm(s1, mC1);
        qv[3][0] = xorm(s1, mD);   qv[3][1] = xorm(s0, mD);
    }
    float4 qcv[4], qsv[4];
    #pragma unroll
    for (int r = 0; r < 4; ++r) {
        int row = wv * 16 + quad * 4 + r;
        qcv[r] = *(float4*)&qtrc[row][0];
        qsv[r] = *(float4*)&qtrs[row][0];
    }
    __syncthreads();   // pss now free for P

    f32x4 Oacc[4] = {{0,0,0,0},{0,0,0,0},{0,0,0,0},{0,0,0,0}};
    float mrow[4] = {-1e30f,-1e30f,-1e30f,-1e30f};
    float lrow[4] = {0.f,0.f,0.f,0.f};

    const float* kb0 = kp  + ((size_t)((b * S_) * H_ + h)) * E_;
    const float* vb0 = vp  + ((size_t)((b * S_) * H_ + h)) * E_;
    const float* kob = ko  + ((size_t)((b * S_) * H_ + h)) * M_;
    const float* ktb = ktt + ((size_t)((b * S_) * H_ + h)) * M_;

    const int kg = t >> 4;   // V-transpose: key group (4 keys)
    const int eg = t & 15;   //              e group (4 e's)

    for (int s0 = 0; s0 < S_; s0 += 64) {
        // ---- stage plain K (fp16, swizzled) ----
        #pragma unroll
        for (int i = 0; i < 4; ++i) {
            int idx = t + NTH * i;
            int key = idx >> 4, c16 = idx & 15;
            float4 kv = *(const float4*)(kb0 + (size_t)(s0 + key) * (H_ * E_) + c16 * 4);
            int k = c16 * 4;
            int ch = ((k >> 3) ^ (key & 7));
            *(f16x4*)&ks_[key][ch * 8 + (k & 7)] = cvt4(kv.x, kv.y, kv.z, kv.w);
        }
        // ---- stage V^T via 4x4 register-block transpose ----
        {
            float4 vr[4];
            #pragma unroll
            for (int j = 0; j < 4; ++j)
                vr[j] = *(const float4*)(vb0 + (size_t)(s0 + kg * 4 + j) * (H_ * E_) + eg * 4);
            #pragma unroll
            for (int e = 0; e < 4; ++e) {
                int row = eg * 4 + e;
                const float* f0 = (const float*)&vr[0];
                const float* f1 = (const float*)&vr[1];
                const float* f2 = (const float*)&vr[2];
                const float* f3 = (const float*)&vr[3];
                int ch = ((kg >> 1) ^ (row & 7));
                *(f16x4*)&vts[row][ch * 8 + (kg & 1) * 4] = cvt4(f0[e], f1[e], f2[e], f3[e]);
            }
        }
        // ---- key trig ----
        {
            int key = t >> 2, m = t & 3;
            size_t off = (size_t)(s0 + key) * (H_ * M_) + m;
            float ang = kob[off] * ((float)(s0 + key) * (1.0f / S_)) + ktb[off];
            ktrc[key][m] = __cosf(ang);
            ktrs[key][m] = __sinf(ang);
        }
        __syncthreads();

        // ---- scores: 16 rows x 64 keys, one plain K frag drives 4 variant MFMAs ----
        float sc[4][4];
        #pragma unroll
        for (int kt2 = 0; kt2 < 4; ++kt2) {
            int keyb = kt2 * 16 + nn;
            f32x4 acc[4] = {{0,0,0,0},{0,0,0,0},{0,0,0,0},{0,0,0,0}};
            #pragma unroll
            for (int ks = 0; ks < 2; ++ks) {
                int ch = ((quad + 4 * ks) ^ (nn & 7)) * 8;
                f16x8 bK = *(f16x8*)&ks_[keyb][ch];
                #pragma unroll
                for (int v = 0; v < 4; ++v)
                    acc[v] = __builtin_amdgcn_mfma_f32_16x16x32_f16(qv[v][ks], bK, acc[v], 0, 0, 0);
            }
            float4 kcv = *(float4*)&ktrc[keyb][0];
            float4 ksv = *(float4*)&ktrs[keyb][0];
            #pragma unroll
            for (int r = 0; r < 4; ++r) {
                float CC = qcv[r].x*kcv.x + qcv[r].y*kcv.y + qcv[r].z*kcv.z + qcv[r].w*kcv.w;
                float CS = qcv[r].x*ksv.x + qcv[r].y*ksv.y + qcv[r].z*ksv.z + qcv[r].w*ksv.w;
                float SC = qsv[r].x*kcv.x + qsv[r].y*kcv.y + qsv[r].z*kcv.z + qsv[r].w*kcv.w;
                float SS = qsv[r].x*ksv.x + qsv[r].y*ksv.y + qsv[r].z*ksv.z + qsv[r].w*ksv.w;
                sc[kt2][r] = (acc[0][r]*CC + acc[1][r]*CS + acc[2][r]*SC + acc[3][r]*SS) * (1.0f/32.0f);
            }
        }

        // ---- online softmax, write P (fp16, swizzled) ----
        #pragma unroll
        for (int r = 0; r < 4; ++r) {
            float tm = fmaxf(fmaxf(sc[0][r], sc[1][r]), fmaxf(sc[2][r], sc[3][r]));
            tm = fmaxf(tm, __shfl_xor(tm, 1));
            tm = fmaxf(tm, __shfl_xor(tm, 2));
            tm = fmaxf(tm, __shfl_xor(tm, 4));
            tm = fmaxf(tm, __shfl_xor(tm, 8));
            float mnew  = fmaxf(mrow[r], tm);
            float alpha = __expf(mrow[r] - mnew);
            int row = wv * 16 + quad * 4 + r;
            float psum = 0.f;
            #pragma unroll
            for (int kt2 = 0; kt2 < 4; ++kt2) {
                float p = __expf(sc[kt2][r] - mnew);
                psum += p;
                int key = kt2 * 16 + nn;
                int ch = ((key >> 3) ^ (row & 7));
                pss[row][ch * 8 + (key & 7)] = (_Float16)p;
            }
            psum += __shfl_xor(psum, 1);
            psum += __shfl_xor(psum, 2);
            psum += __shfl_xor(psum, 4);
            psum += __shfl_xor(psum, 8);
            lrow[r] = lrow[r] * alpha + psum;
            mrow[r] = mnew;
            Oacc[0][r] *= alpha; Oacc[1][r] *= alpha;
            Oacc[2][r] *= alpha; Oacc[3][r] *= alpha;
        }

        // ---- PV (wave-local P round-trip, no barrier needed) ----
        {
            int prow = wv * 16 + nn;
            #pragma unroll
            for (int ks = 0; ks < 2; ++ks) {
                int chp = ((quad + 4 * ks) ^ (prow & 7)) * 8;
                f16x8 pf = *(f16x8*)&pss[prow][chp];
                #pragma unroll
                for (int et = 0; et < 4; ++et) {
                    int e = et * 16 + nn;
                    int chv = ((quad + 4 * ks) ^ (e & 7)) * 8;
                    f16x8 vf = *(f16x8*)&vts[e][chv];
                    Oacc[et] = __builtin_amdgcn_mfma_f32_16x16x32_f16(pf, vf, Oacc[et], 0, 0, 0);
                }
            }
        }
        __syncthreads();   // protect ks_/vts/trig before next staging
    }

    // ---- epilogue ----
    float* ob = out + ((size_t)((b * L_ + l0) * H_ + h)) * E_;
    #pragma unroll
    for (int r = 0; r < 4; ++r) {
        float inv = 1.0f / lrow[r];
        int row = wv * 16 + quad * 4 + r;
        #pragma unroll
        for (int et = 0; et < 4; ++et) {
            ob[(size_t)row * (H_ * E_) + et * 16 + nn] = Oacc[et][r] * inv;
        }
    }
}

extern "C" void kernel_launch(void* const* d_in, const int* in_sizes, int n_in,
                              void* d_out, int out_size, void* d_ws, size_t ws_size,
                              hipStream_t stream) {
    const float* qp = (const float*)d_in[0];
    const float* kp = (const float*)d_in[1];
    const float* vp = (const float*)d_in[2];
    const float* qo = (const float*)d_in[3];
    const float* qt = (const float*)d_in[4];
    const float* ko = (const float*)d_in[5];
    const float* kt = (const float*)d_in[6];
    float* out = (float*)d_out;

    dim3 grid(L_ / 64, H_, B_);
    qattn_mfma2<<<grid, dim3(NTH), 0, stream>>>(qp, kp, vp, qo, qt, ko, kt, out);
}